// Round 2
// baseline (446.167 us; speedup 1.0000x reference)
//
#include <hip/hip_runtime.h>
#include <hip/hip_bf16.h>

#define NEG_SLOPE 0.2f

__device__ __forceinline__ float lrelu(float v) { return v > 0.0f ? v : NEG_SLOPE * v; }

// ---------------- GEMM: h = x @ W  (N x 128) @ (128 x 128) ----------------
// 512 threads/block, 128 rows/block. W staged in LDS in two 64-row k-halves.
// Each thread: 8 rows x 4 cols = 32 accumulators.
__global__ __launch_bounds__(512) void k_gemm(const float* __restrict__ x,
                                              const float* __restrict__ W,
                                              float* __restrict__ h, int N) {
    __shared__ float ws[64 * 128];   // 32 KB: k-half of W, row-major [k][128]
    __shared__ float xs[128 * 64];   // 32 KB: 128 rows x 64 k, row-major stride 64
    int t = threadIdx.x;
    int tx = t & 31;     // col group: cols tx*4 .. tx*4+3
    int ty = t >> 5;     // 0..15: rows ty*8 .. ty*8+7
    int row0 = blockIdx.x * 128;

    float4 acc[8];
#pragma unroll
    for (int r = 0; r < 8; ++r) acc[r] = float4{0.f, 0.f, 0.f, 0.f};

    for (int kh = 0; kh < 2; ++kh) {
        __syncthreads();  // protect previous iteration's LDS reads
        for (int i = t; i < 2048; i += 512)
            ((float4*)ws)[i] = ((const float4*)W)[kh * 2048 + i];
        for (int i = t; i < 2048; i += 512) {
            int r = i >> 4, c4 = i & 15;
            int gr = row0 + r;
            float4 v = float4{0.f, 0.f, 0.f, 0.f};
            if (gr < N) v = ((const float4*)x)[(size_t)gr * 32 + kh * 16 + c4];
            ((float4*)xs)[i] = v;
        }
        __syncthreads();
#pragma unroll 4
        for (int k = 0; k < 64; ++k) {
            float4 wv = *(float4*)&ws[k * 128 + tx * 4];
#pragma unroll
            for (int r = 0; r < 8; ++r) {
                float xv = xs[(ty * 8 + r) * 64 + k];
                acc[r].x = fmaf(xv, wv.x, acc[r].x);
                acc[r].y = fmaf(xv, wv.y, acc[r].y);
                acc[r].z = fmaf(xv, wv.z, acc[r].z);
                acc[r].w = fmaf(xv, wv.w, acc[r].w);
            }
        }
    }
#pragma unroll
    for (int r = 0; r < 8; ++r) {
        int gr = row0 + ty * 8 + r;
        if (gr < N) ((float4*)h)[(size_t)gr * 32 + tx] = acc[r];
    }
}

// ---------------- per-node attention logits: a_src/a_dst [N,4] ----------------
__global__ __launch_bounds__(256) void k_att(const float* __restrict__ h,
                                             const float* __restrict__ att_src,
                                             const float* __restrict__ att_dst,
                                             float* __restrict__ a_src,
                                             float* __restrict__ a_dst, int N) {
    int t = threadIdx.x;
    int n = blockIdx.x * 2 + (t >> 7);
    if (n >= N) return;
    int c = t & 127;
    float hv = h[(size_t)n * 128 + c];
    float vs = hv * att_src[c];
    float vd = hv * att_dst[c];
#pragma unroll
    for (int m = 16; m >= 1; m >>= 1) {
        vs += __shfl_xor(vs, m);
        vd += __shfl_xor(vd, m);
    }
    if ((c & 31) == 0) {
        a_src[n * 4 + (c >> 5)] = vs;
        a_dst[n * 4 + (c >> 5)] = vd;
    }
}

// ---------------- degree histogram over dst ----------------
__global__ void k_deg(const int* __restrict__ ei, int E, unsigned* __restrict__ deg) {
    int e = blockIdx.x * 256 + threadIdx.x;
    if (e < E) atomicAdd(&deg[ei[(size_t)E + e]], 1u);
}

// ---------------- exclusive scan (3 kernels) ----------------
__global__ void k_scan1(const unsigned* __restrict__ deg, unsigned* __restrict__ part,
                        unsigned* __restrict__ blockSums, int N) {
    __shared__ unsigned s[256];
    int t = threadIdx.x;
    int i = blockIdx.x * 256 + t;
    unsigned v = (i < N) ? deg[i] : 0u;
    s[t] = v;
    __syncthreads();
    for (int off = 1; off < 256; off <<= 1) {
        unsigned a = (t >= off) ? s[t - off] : 0u;
        __syncthreads();
        s[t] += a;
        __syncthreads();
    }
    if (i < N) part[i] = s[t] - v;  // exclusive
    if (t == 255) blockSums[blockIdx.x] = s[255];
}

__global__ void k_scan2(const unsigned* __restrict__ blockSums,
                        unsigned* __restrict__ blockScan, int NB) {
    __shared__ unsigned s[512];
    int t = threadIdx.x;
    unsigned v = (t < NB) ? blockSums[t] : 0u;
    s[t] = v;
    __syncthreads();
    for (int off = 1; off < 512; off <<= 1) {
        unsigned a = (t >= off) ? s[t - off] : 0u;
        __syncthreads();
        s[t] += a;
        __syncthreads();
    }
    if (t < NB) blockScan[t] = s[t] - v;  // exclusive
}

__global__ void k_scan3(unsigned* __restrict__ part, const unsigned* __restrict__ blockScan, int N) {
    int i = blockIdx.x * 256 + threadIdx.x;
    if (i < N) part[i] += blockScan[blockIdx.x];
}

// ---------------- scatter edges into CSR (by dst) ----------------
__global__ void k_scatter(const int* __restrict__ ei, int E,
                          const unsigned* __restrict__ offsets, unsigned* __restrict__ cursor,
                          int* __restrict__ csr_src) {
    int e = blockIdx.x * 256 + threadIdx.x;
    if (e >= E) return;
    int s = ei[e];
    int d = ei[(size_t)E + e];
    unsigned pos = offsets[d] + atomicAdd(&cursor[d], 1u);
    csr_src[pos] = s;
}

// ---------------- gather: one wave per dst node ----------------
__global__ __launch_bounds__(256) void k_gather(const float* __restrict__ h,
                                                const int* __restrict__ csr_src,
                                                const unsigned* __restrict__ offsets,
                                                const unsigned* __restrict__ deg,
                                                const float* __restrict__ a_src,
                                                const float* __restrict__ a_dst,
                                                const float* __restrict__ bias,
                                                float* __restrict__ out, int N) {
    int n = (int)((blockIdx.x * 256 + threadIdx.x) >> 6);
    int lane = threadIdx.x & 63;
    if (n >= N) return;
    int head = lane >> 4;  // channel pair 2*lane,2*lane+1 -> head = lane/16
    unsigned off = offsets[n];
    unsigned dg = deg[n];
    const float2* __restrict__ h2 = (const float2*)h;
    float ad_n = a_dst[n * 4 + head];
    float ax = 0.f, ay = 0.f, dsum = 0.f;
    for (unsigned e = off; e < off + dg; ++e) {
        int s = csr_src[e];
        float p = __expf(lrelu(a_src[s * 4 + head] + ad_n));
        float2 hv = h2[(size_t)s * 64 + lane];
        ax = fmaf(p, hv.x, ax);
        ay = fmaf(p, hv.y, ay);
        dsum += p;
    }
    // self loop
    float p_self = __expf(lrelu(a_src[n * 4 + head] + ad_n));
    float2 hs = h2[(size_t)n * 64 + lane];
    ax = fmaf(p_self, hs.x, ax);
    ay = fmaf(p_self, hs.y, ay);
    dsum += p_self;
    float inv = 1.0f / dsum;
    float2 b = ((const float2*)bias)[lane];
    float ox = ax * inv + b.x;
    float oy = ay * inv + b.y;
    ox = ox > 0.f ? ox : (__expf(ox) - 1.0f);
    oy = oy > 0.f ? oy : (__expf(oy) - 1.0f);
    ((float2*)out)[(size_t)n * 64 + lane] = float2{ox, oy};
}

extern "C" void kernel_launch(void* const* d_in, const int* in_sizes, int n_in,
                              void* d_out, int out_size, void* d_ws, size_t ws_size,
                              hipStream_t stream) {
    const float* x = (const float*)d_in[0];
    const int* ei = (const int*)d_in[1];          // int32 per harness convention
    const float* W = (const float*)d_in[2];
    const float* att_src = (const float*)d_in[3];
    const float* att_dst = (const float*)d_in[4];
    const float* bias = (const float*)d_in[5];
    int N = in_sizes[0] / 128;
    int E = in_sizes[1] / 2;

    char* ws = (char*)d_ws;
    size_t o = 0;
    float* h = (float*)(ws + o);          o += (size_t)N * 128 * 4;  // 51.2 MB
    float* a_src = (float*)(ws + o);      o += (size_t)N * 4 * 4;
    float* a_dst = (float*)(ws + o);      o += (size_t)N * 4 * 4;
    int* csr_src = (int*)(ws + o);        o += (size_t)E * 4;        // 6.4 MB
    unsigned* deg = (unsigned*)(ws + o);  o += (size_t)N * 4;
    unsigned* offs = (unsigned*)(ws + o); o += (size_t)N * 4;
    unsigned* cur = (unsigned*)(ws + o);  o += (size_t)N * 4;
    unsigned* blockSums = (unsigned*)(ws + o); o += 2048;
    unsigned* blockScan = (unsigned*)(ws + o); o += 2048;

    hipMemsetAsync(deg, 0, (size_t)N * 4, stream);
    hipMemsetAsync(cur, 0, (size_t)N * 4, stream);

    k_gemm<<<(N + 127) / 128, 512, 0, stream>>>(x, W, h, N);
    k_att<<<(N + 1) / 2, 256, 0, stream>>>(h, att_src, att_dst, a_src, a_dst, N);
    k_deg<<<(E + 255) / 256, 256, 0, stream>>>(ei, E, deg);
    int NB = (N + 255) / 256;  // 391 <= 512
    k_scan1<<<NB, 256, 0, stream>>>(deg, offs, blockSums, N);
    k_scan2<<<1, 512, 0, stream>>>(blockSums, blockScan, NB);
    k_scan3<<<NB, 256, 0, stream>>>(offs, blockScan, N);
    k_scatter<<<(E + 255) / 256, 256, 0, stream>>>(ei, E, offs, cur, csr_src);
    k_gather<<<(N + 3) / 4, 256, 0, stream>>>(h, csr_src, offs, deg, a_src, a_dst, bias,
                                              (float*)d_out, N);
}

// Round 3
// 422.310 us; speedup vs baseline: 1.0565x; 1.0565x over previous
//
#include <hip/hip_runtime.h>
#include <hip/hip_bf16.h>

#define NEG_SLOPE 0.2f

__device__ __forceinline__ float lrelu(float v) { return v > 0.0f ? v : NEG_SLOPE * v; }

__device__ __forceinline__ unsigned bf16pair(float a, float b) {
    unsigned ua = __float_as_uint(a), ub = __float_as_uint(b);
    ua = (ua + 0x7FFFu + ((ua >> 16) & 1u)) >> 16;
    ub = (ub + 0x7FFFu + ((ub >> 16) & 1u)) >> 16;
    return ua | (ub << 16);
}

// ---------------- GEMM: h = x @ W, fused attention logits ----------------
// 512 threads/block, 128 rows/block, fp32 compute. Epilogue: write h as bf16
// and reduce a_src/a_dst per (row, head) via 8-lane shuffles.
__global__ __launch_bounds__(512) void k_gemm(const float* __restrict__ x,
                                              const float* __restrict__ W,
                                              const float* __restrict__ att_src,
                                              const float* __restrict__ att_dst,
                                              unsigned* __restrict__ hb,   // [N][64] uint (bf16x2)
                                              float* __restrict__ a_src,
                                              float* __restrict__ a_dst, int N) {
    __shared__ float ws[64 * 128];   // 32 KB: k-half of W, row-major [k][128]
    __shared__ float xs[128 * 64];   // 32 KB: 128 rows x 64 k
    int t = threadIdx.x;
    int tx = t & 31;     // cols tx*4 .. tx*4+3
    int ty = t >> 5;     // rows ty*8 .. ty*8+7
    int row0 = blockIdx.x * 128;

    float4 acc[8];
#pragma unroll
    for (int r = 0; r < 8; ++r) acc[r] = float4{0.f, 0.f, 0.f, 0.f};

    for (int kh = 0; kh < 2; ++kh) {
        __syncthreads();
        for (int i = t; i < 2048; i += 512)
            ((float4*)ws)[i] = ((const float4*)W)[kh * 2048 + i];
        for (int i = t; i < 2048; i += 512) {
            int r = i >> 4, c4 = i & 15;
            int gr = row0 + r;
            float4 v = float4{0.f, 0.f, 0.f, 0.f};
            if (gr < N) v = ((const float4*)x)[(size_t)gr * 32 + kh * 16 + c4];
            ((float4*)xs)[i] = v;
        }
        __syncthreads();
#pragma unroll 4
        for (int k = 0; k < 64; ++k) {
            float4 wv = *(float4*)&ws[k * 128 + tx * 4];
#pragma unroll
            for (int r = 0; r < 8; ++r) {
                float xv = xs[(ty * 8 + r) * 64 + k];
                acc[r].x = fmaf(xv, wv.x, acc[r].x);
                acc[r].y = fmaf(xv, wv.y, acc[r].y);
                acc[r].z = fmaf(xv, wv.z, acc[r].z);
                acc[r].w = fmaf(xv, wv.w, acc[r].w);
            }
        }
    }
    // epilogue: h (bf16) + fused a_src/a_dst
    float4 av_s = ((const float4*)att_src)[tx];
    float4 av_d = ((const float4*)att_dst)[tx];
#pragma unroll
    for (int r = 0; r < 8; ++r) {
        int gr = row0 + ty * 8 + r;
        float ps = acc[r].x * av_s.x + acc[r].y * av_s.y + acc[r].z * av_s.z + acc[r].w * av_s.w;
        float pd = acc[r].x * av_d.x + acc[r].y * av_d.y + acc[r].z * av_d.z + acc[r].w * av_d.w;
#pragma unroll
        for (int m = 1; m <= 4; m <<= 1) {
            ps += __shfl_xor(ps, m);
            pd += __shfl_xor(pd, m);
        }
        if (gr < N) {
            uint2 hv;
            hv.x = bf16pair(acc[r].x, acc[r].y);
            hv.y = bf16pair(acc[r].z, acc[r].w);
            ((uint2*)hb)[(size_t)gr * 32 + tx] = hv;
            if ((tx & 7) == 0) {
                a_src[gr * 4 + (tx >> 3)] = ps;
                a_dst[gr * 4 + (tx >> 3)] = pd;
            }
        }
    }
}

// ---------------- degree histogram over dst ----------------
__global__ void k_deg(const int* __restrict__ ei, int E, unsigned* __restrict__ deg) {
    int e = blockIdx.x * 256 + threadIdx.x;
    if (e < E) atomicAdd(&deg[ei[(size_t)E + e]], 1u);
}

// ---------------- exclusive scan (3 kernels) ----------------
__global__ void k_scan1(const unsigned* __restrict__ deg, unsigned* __restrict__ part,
                        unsigned* __restrict__ blockSums, int N) {
    __shared__ unsigned s[256];
    int t = threadIdx.x;
    int i = blockIdx.x * 256 + t;
    unsigned v = (i < N) ? deg[i] : 0u;
    s[t] = v;
    __syncthreads();
    for (int off = 1; off < 256; off <<= 1) {
        unsigned a = (t >= off) ? s[t - off] : 0u;
        __syncthreads();
        s[t] += a;
        __syncthreads();
    }
    if (i < N) part[i] = s[t] - v;
    if (t == 255) blockSums[blockIdx.x] = s[255];
}

__global__ void k_scan2(const unsigned* __restrict__ blockSums,
                        unsigned* __restrict__ blockScan, int NB) {
    __shared__ unsigned s[512];
    int t = threadIdx.x;
    unsigned v = (t < NB) ? blockSums[t] : 0u;
    s[t] = v;
    __syncthreads();
    for (int off = 1; off < 512; off <<= 1) {
        unsigned a = (t >= off) ? s[t - off] : 0u;
        __syncthreads();
        s[t] += a;
        __syncthreads();
    }
    if (t < NB) blockScan[t] = s[t] - v;
}

__global__ void k_scan3(unsigned* __restrict__ part, const unsigned* __restrict__ blockScan, int N) {
    int i = blockIdx.x * 256 + threadIdx.x;
    if (i < N) part[i] += blockScan[blockIdx.x];
}

// ---------------- scatter edges into CSR (by dst) ----------------
__global__ void k_scatter(const int* __restrict__ ei, int E,
                          const unsigned* __restrict__ offsets, unsigned* __restrict__ cursor,
                          int* __restrict__ csr_src) {
    int e = blockIdx.x * 256 + threadIdx.x;
    if (e >= E) return;
    int s = ei[e];
    int d = ei[(size_t)E + e];
    unsigned pos = offsets[d] + atomicAdd(&cursor[d], 1u);
    csr_src[pos] = s;
}

// ---------------- gather: one wave per dst node, bf16 h ----------------
__global__ __launch_bounds__(512) void k_gather(const unsigned* __restrict__ hb,
                                                const int* __restrict__ csr_src,
                                                const unsigned* __restrict__ offsets,
                                                const unsigned* __restrict__ deg,
                                                const float* __restrict__ a_src,
                                                const float* __restrict__ a_dst,
                                                const float* __restrict__ bias,
                                                float* __restrict__ out, int N) {
    int n = (int)((blockIdx.x * 512 + threadIdx.x) >> 6);
    int lane = threadIdx.x & 63;
    if (n >= N) return;
    int head = lane >> 4;  // channels 2*lane, 2*lane+1
    unsigned off = offsets[n];
    unsigned dg = deg[n];
    float ad_n = a_dst[n * 4 + head];
    float ax = 0.f, ay = 0.f, dsum = 0.f;
    for (unsigned e = off; e < off + dg; ++e) {
        int s = csr_src[e];
        float p = __expf(lrelu(a_src[s * 4 + head] + ad_n));
        unsigned u = hb[(size_t)s * 64 + lane];
        float hx = __uint_as_float(u << 16);
        float hy = __uint_as_float(u & 0xFFFF0000u);
        ax = fmaf(p, hx, ax);
        ay = fmaf(p, hy, ay);
        dsum += p;
    }
    // self loop
    float p_self = __expf(lrelu(a_src[n * 4 + head] + ad_n));
    unsigned us = hb[(size_t)n * 64 + lane];
    ax = fmaf(p_self, __uint_as_float(us << 16), ax);
    ay = fmaf(p_self, __uint_as_float(us & 0xFFFF0000u), ay);
    dsum += p_self;
    float inv = 1.0f / dsum;
    float2 b = ((const float2*)bias)[lane];
    float ox = ax * inv + b.x;
    float oy = ay * inv + b.y;
    ox = ox > 0.f ? ox : (__expf(ox) - 1.0f);
    oy = oy > 0.f ? oy : (__expf(oy) - 1.0f);
    ((float2*)out)[(size_t)n * 64 + lane] = float2{ox, oy};
}

extern "C" void kernel_launch(void* const* d_in, const int* in_sizes, int n_in,
                              void* d_out, int out_size, void* d_ws, size_t ws_size,
                              hipStream_t stream) {
    const float* x = (const float*)d_in[0];
    const int* ei = (const int*)d_in[1];
    const float* W = (const float*)d_in[2];
    const float* att_src = (const float*)d_in[3];
    const float* att_dst = (const float*)d_in[4];
    const float* bias = (const float*)d_in[5];
    int N = in_sizes[0] / 128;
    int E = in_sizes[1] / 2;

    char* ws = (char*)d_ws;
    size_t o = 0;
    unsigned* hb = (unsigned*)(ws + o);   o += (size_t)N * 64 * 4;   // 25.6 MB bf16 h
    float* a_src = (float*)(ws + o);      o += (size_t)N * 4 * 4;
    float* a_dst = (float*)(ws + o);      o += (size_t)N * 4 * 4;
    int* csr_src = (int*)(ws + o);        o += (size_t)E * 4;        // 6.4 MB
    unsigned* deg = (unsigned*)(ws + o);  o += (size_t)N * 4;
    unsigned* cur = (unsigned*)(ws + o);  o += (size_t)N * 4;        // adjacent to deg
    unsigned* offs = (unsigned*)(ws + o); o += (size_t)N * 4;
    unsigned* blockSums = (unsigned*)(ws + o); o += 2048;
    unsigned* blockScan = (unsigned*)(ws + o); o += 2048;

    hipMemsetAsync(deg, 0, (size_t)N * 8, stream);  // deg + cur in one call

    k_gemm<<<(N + 127) / 128, 512, 0, stream>>>(x, W, att_src, att_dst, hb, a_src, a_dst, N);
    k_deg<<<(E + 255) / 256, 256, 0, stream>>>(ei, E, deg);
    int NB = (N + 255) / 256;  // 391 <= 512
    k_scan1<<<NB, 256, 0, stream>>>(deg, offs, blockSums, N);
    k_scan2<<<1, 512, 0, stream>>>(blockSums, blockScan, NB);
    k_scan3<<<NB, 256, 0, stream>>>(offs, blockScan, N);
    k_scatter<<<(E + 255) / 256, 256, 0, stream>>>(ei, E, offs, cur, csr_src);
    k_gather<<<(N * 64 + 511) / 512, 512, 0, stream>>>(hb, csr_src, offs, deg, a_src, a_dst,
                                                       bias, (float*)d_out, N);
}

// Round 4
// 300.540 us; speedup vs baseline: 1.4846x; 1.4052x over previous
//
#include <hip/hip_runtime.h>
#include <hip/hip_bf16.h>

#define NEG_SLOPE 0.2f

typedef __attribute__((ext_vector_type(8))) short bf16x8;
typedef __attribute__((ext_vector_type(4))) float f32x4;

__device__ __forceinline__ float lrelu(float v) { return v > 0.0f ? v : NEG_SLOPE * v; }

__device__ __forceinline__ unsigned bf16pair(float a, float b) {
    unsigned ua = __float_as_uint(a), ub = __float_as_uint(b);
    ua = (ua + 0x7FFFu + ((ua >> 16) & 1u)) >> 16;
    ub = (ub + 0x7FFFu + ((ub >> 16) & 1u)) >> 16;
    return ua | (ub << 16);
}

// ---------------- prep: Wt[n][k] = bf16(W[k][n]) ----------------
__global__ __launch_bounds__(256) void k_prep(const float* __restrict__ W,
                                              unsigned short* __restrict__ Wt) {
    int t = threadIdx.x;
    int n = t >> 1, kh = (t & 1) * 64;
    for (int k = 0; k < 64; ++k) {
        float v = W[(size_t)(kh + k) * 128 + n];
        unsigned u = __float_as_uint(v);
        u = (u + 0x7FFFu + ((u >> 16) & 1u)) >> 16;
        Wt[n * 128 + kh + k] = (unsigned short)u;
    }
}

// ---------------- MFMA GEMM: h=x@W (bf16 in, fp32 acc), fused att logits ----
// 256 threads (4 waves), 128 rows x 128 cols per block, K=128 in LDS.
__global__ __launch_bounds__(256) void k_gemm(const float* __restrict__ x,
                                              const unsigned short* __restrict__ Wt,
                                              const float* __restrict__ att_src,
                                              const float* __restrict__ att_dst,
                                              unsigned* __restrict__ hb,
                                              float* __restrict__ a_src,
                                              float* __restrict__ a_dst, int N) {
    __shared__ unsigned char smA[32768];  // A tile: [128 rows][128 k] bf16, 16B-chunk XOR swizzle
    __shared__ unsigned char smB[32768];  // Wt tile: [128 cols][128 k] bf16, same swizzle
    int t = threadIdx.x;
    int row0 = blockIdx.x * 128;

    // stage A (x -> bf16, swizzled)
    {
        int r = t >> 1, halfc = t & 1;
        int gr = row0 + r;
#pragma unroll
        for (int j = 0; j < 8; ++j) {
            float4 f0 = {0.f, 0.f, 0.f, 0.f}, f1 = {0.f, 0.f, 0.f, 0.f};
            if (gr < N) {
                f0 = ((const float4*)x)[(size_t)gr * 32 + halfc * 16 + j * 2];
                f1 = ((const float4*)x)[(size_t)gr * 32 + halfc * 16 + j * 2 + 1];
            }
            uint4 u;
            u.x = bf16pair(f0.x, f0.y);
            u.y = bf16pair(f0.z, f0.w);
            u.z = bf16pair(f1.x, f1.y);
            u.w = bf16pair(f1.z, f1.w);
            int c = halfc * 8 + j;
            *(uint4*)&smA[r * 256 + ((c ^ (r & 7)) * 16)] = u;
        }
        // stage Wt (already bf16, swizzled)
        int n = t >> 1;
#pragma unroll
        for (int j = 0; j < 8; ++j) {
            int c = halfc * 8 + j;
            uint4 u = ((const uint4*)Wt)[n * 16 + c];
            *(uint4*)&smB[n * 256 + ((c ^ (n & 7)) * 16)] = u;
        }
    }
    __syncthreads();

    int w = t >> 6, lane = t & 63;
    int lr = lane & 15, lg = lane >> 4;

    f32x4 acc[2][8];
#pragma unroll
    for (int i = 0; i < 2; ++i)
#pragma unroll
        for (int j = 0; j < 8; ++j)
#pragma unroll
            for (int q = 0; q < 4; ++q) acc[i][j][q] = 0.f;

#pragma unroll
    for (int kc = 0; kc < 4; ++kc) {
        bf16x8 av[2], bv[8];
#pragma unroll
        for (int rf = 0; rf < 2; ++rf) {
            int ar = w * 32 + rf * 16 + lr;
            av[rf] = *(const bf16x8*)&smA[ar * 256 + (((kc * 4 + lg) ^ (ar & 7)) * 16)];
        }
#pragma unroll
        for (int cf = 0; cf < 8; ++cf) {
            int bc = cf * 16 + lr;
            bv[cf] = *(const bf16x8*)&smB[bc * 256 + (((kc * 4 + lg) ^ (bc & 7)) * 16)];
        }
#pragma unroll
        for (int rf = 0; rf < 2; ++rf)
#pragma unroll
            for (int cf = 0; cf < 8; ++cf)
                acc[rf][cf] = __builtin_amdgcn_mfma_f32_16x16x32_bf16(av[rf], bv[cf], acc[rf][cf], 0, 0, 0);
    }

    // epilogue: hb (bf16 pairs) + fused a_src/a_dst
    float att_s[8], att_d[8];
#pragma unroll
    for (int cf = 0; cf < 8; ++cf) {
        att_s[cf] = att_src[cf * 16 + lr];
        att_d[cf] = att_dst[cf * 16 + lr];
    }
#pragma unroll
    for (int rf = 0; rf < 2; ++rf) {
#pragma unroll
        for (int reg = 0; reg < 4; ++reg) {
            int row = row0 + w * 32 + rf * 16 + lg * 4 + reg;
            // attention partials: head hh covers col-frags 2hh, 2hh+1
            float ps[4], pd[4];
#pragma unroll
            for (int hh = 0; hh < 4; ++hh) {
                ps[hh] = acc[rf][2 * hh][reg] * att_s[2 * hh] + acc[rf][2 * hh + 1][reg] * att_s[2 * hh + 1];
                pd[hh] = acc[rf][2 * hh][reg] * att_d[2 * hh] + acc[rf][2 * hh + 1][reg] * att_d[2 * hh + 1];
            }
#pragma unroll
            for (int m = 1; m <= 8; m <<= 1) {
#pragma unroll
                for (int hh = 0; hh < 4; ++hh) {
                    ps[hh] += __shfl_xor(ps[hh], m);
                    pd[hh] += __shfl_xor(pd[hh], m);
                }
            }
            if (lr == 0 && row < N) {
                ((float4*)a_src)[row] = float4{ps[0], ps[1], ps[2], ps[3]};
                ((float4*)a_dst)[row] = float4{pd[0], pd[1], pd[2], pd[3]};
            }
            // hb: pair adjacent cols via shfl, even lanes store u32
#pragma unroll
            for (int cf = 0; cf < 8; ++cf) {
                float v = acc[rf][cf][reg];
                float vo = __shfl_xor(v, 1);
                if (!(lane & 1) && row < N)
                    hb[(size_t)row * 64 + cf * 8 + (lr >> 1)] = bf16pair(v, vo);
            }
        }
    }
}

// ---------------- degree histogram over dst ----------------
__global__ void k_deg(const int* __restrict__ ei, int E, unsigned* __restrict__ deg) {
    int e = blockIdx.x * 256 + threadIdx.x;
    if (e < E) atomicAdd(&deg[ei[(size_t)E + e]], 1u);
}

// ---------------- exclusive scan (3 kernels) ----------------
__global__ void k_scan1(const unsigned* __restrict__ deg, unsigned* __restrict__ part,
                        unsigned* __restrict__ blockSums, int N) {
    __shared__ unsigned s[256];
    int t = threadIdx.x;
    int i = blockIdx.x * 256 + t;
    unsigned v = (i < N) ? deg[i] : 0u;
    s[t] = v;
    __syncthreads();
    for (int off = 1; off < 256; off <<= 1) {
        unsigned a = (t >= off) ? s[t - off] : 0u;
        __syncthreads();
        s[t] += a;
        __syncthreads();
    }
    if (i < N) part[i] = s[t] - v;
    if (t == 255) blockSums[blockIdx.x] = s[255];
}

__global__ void k_scan2(const unsigned* __restrict__ blockSums,
                        unsigned* __restrict__ blockScan, int NB) {
    __shared__ unsigned s[512];
    int t = threadIdx.x;
    unsigned v = (t < NB) ? blockSums[t] : 0u;
    s[t] = v;
    __syncthreads();
    for (int off = 1; off < 512; off <<= 1) {
        unsigned a = (t >= off) ? s[t - off] : 0u;
        __syncthreads();
        s[t] += a;
        __syncthreads();
    }
    if (t < NB) blockScan[t] = s[t] - v;
}

__global__ void k_scan3(unsigned* __restrict__ part, const unsigned* __restrict__ blockScan, int N) {
    int i = blockIdx.x * 256 + threadIdx.x;
    if (i < N) part[i] += blockScan[blockIdx.x];
}

// ---------------- scatter: build 16B CSR entries {src, p01_f16, p23_f16, 0} --
__global__ void k_scatter(const int* __restrict__ ei, int E,
                          const float* __restrict__ a_src, const float* __restrict__ a_dst,
                          const unsigned* __restrict__ offsets, unsigned* __restrict__ cursor,
                          uint4* __restrict__ csr) {
    int e = blockIdx.x * 256 + threadIdx.x;
    if (e >= E) return;
    int s = ei[e];
    int d = ei[(size_t)E + e];
    float4 as = ((const float4*)a_src)[s];
    float4 ad = ((const float4*)a_dst)[d];
    float p0 = __expf(lrelu(as.x + ad.x));
    float p1 = __expf(lrelu(as.y + ad.y));
    float p2 = __expf(lrelu(as.z + ad.z));
    float p3 = __expf(lrelu(as.w + ad.w));
    unsigned p01 = __builtin_bit_cast(unsigned, __builtin_amdgcn_cvt_pkrtz(p0, p1));
    unsigned p23 = __builtin_bit_cast(unsigned, __builtin_amdgcn_cvt_pkrtz(p2, p3));
    unsigned pos = offsets[d] + atomicAdd(&cursor[d], 1u);
    csr[pos] = uint4{(unsigned)s, p01, p23, 0u};
}

// ---------------- gather: one wave per dst node, 8-wide MLP ----------------
#define GSTEP(E_)                                                                   \
    {                                                                               \
        unsigned pw = (head & 2) ? E_.z : E_.y;                                     \
        unsigned hv = (head & 1) ? (pw >> 16) : (pw & 0xFFFFu);                     \
        float p = (float)__builtin_bit_cast(_Float16, (unsigned short)hv);          \
        unsigned u = hb[(size_t)E_.x * 64 + lane];                                  \
        ax = fmaf(p, __uint_as_float(u << 16), ax);                                 \
        ay = fmaf(p, __uint_as_float(u & 0xFFFF0000u), ay);                         \
        dsum += p;                                                                  \
    }

__global__ __launch_bounds__(512) void k_gather(const unsigned* __restrict__ hb,
                                                const uint4* __restrict__ csr,
                                                const unsigned* __restrict__ offsets,
                                                const unsigned* __restrict__ deg,
                                                const float* __restrict__ a_src,
                                                const float* __restrict__ a_dst,
                                                const float* __restrict__ bias,
                                                float* __restrict__ out, int N) {
    int n = (int)((blockIdx.x * 512 + threadIdx.x) >> 6);
    int lane = threadIdx.x & 63;
    if (n >= N) return;
    int head = lane >> 4;
    unsigned e = offsets[n];
    unsigned end = e + deg[n];
    float ax = 0.f, ay = 0.f, dsum = 0.f;
    while (e + 8 <= end) {
        uint4 E0 = csr[e + 0], E1 = csr[e + 1], E2 = csr[e + 2], E3 = csr[e + 3];
        uint4 E4 = csr[e + 4], E5 = csr[e + 5], E6 = csr[e + 6], E7 = csr[e + 7];
        GSTEP(E0) GSTEP(E1) GSTEP(E2) GSTEP(E3)
        GSTEP(E4) GSTEP(E5) GSTEP(E6) GSTEP(E7)
        e += 8;
    }
    while (e < end) {
        uint4 E0 = csr[e];
        GSTEP(E0)
        ++e;
    }
    // self loop (fp32 p)
    float p_self = __expf(lrelu(a_src[n * 4 + head] + a_dst[n * 4 + head]));
    unsigned us = hb[(size_t)n * 64 + lane];
    ax = fmaf(p_self, __uint_as_float(us << 16), ax);
    ay = fmaf(p_self, __uint_as_float(us & 0xFFFF0000u), ay);
    dsum += p_self;
    float inv = 1.0f / dsum;
    float2 b = ((const float2*)bias)[lane];
    float ox = ax * inv + b.x;
    float oy = ay * inv + b.y;
    ox = ox > 0.f ? ox : (__expf(ox) - 1.0f);
    oy = oy > 0.f ? oy : (__expf(oy) - 1.0f);
    ((float2*)out)[(size_t)n * 64 + lane] = float2{ox, oy};
}

extern "C" void kernel_launch(void* const* d_in, const int* in_sizes, int n_in,
                              void* d_out, int out_size, void* d_ws, size_t ws_size,
                              hipStream_t stream) {
    const float* x = (const float*)d_in[0];
    const int* ei = (const int*)d_in[1];
    const float* W = (const float*)d_in[2];
    const float* att_src = (const float*)d_in[3];
    const float* att_dst = (const float*)d_in[4];
    const float* bias = (const float*)d_in[5];
    int N = in_sizes[0] / 128;
    int E = in_sizes[1] / 2;

    char* ws = (char*)d_ws;
    size_t o = 0;
    unsigned* hb = (unsigned*)(ws + o);   o += (size_t)N * 64 * 4;   // 25.6 MB bf16 h
    float* a_src = (float*)(ws + o);      o += (size_t)N * 4 * 4;
    float* a_dst = (float*)(ws + o);      o += (size_t)N * 4 * 4;
    uint4* csr = (uint4*)(ws + o);        o += (size_t)E * 16;       // 25.6 MB
    unsigned short* Wt = (unsigned short*)(ws + o); o += 128 * 128 * 2;
    unsigned* deg = (unsigned*)(ws + o);  o += (size_t)N * 4;
    unsigned* cur = (unsigned*)(ws + o);  o += (size_t)N * 4;
    unsigned* offs = (unsigned*)(ws + o); o += (size_t)N * 4;
    unsigned* blockSums = (unsigned*)(ws + o); o += 2048;
    unsigned* blockScan = (unsigned*)(ws + o); o += 2048;

    hipMemsetAsync(deg, 0, (size_t)N * 8, stream);  // deg + cur

    k_prep<<<1, 256, 0, stream>>>(W, Wt);
    k_gemm<<<(N + 127) / 128, 256, 0, stream>>>(x, Wt, att_src, att_dst, hb, a_src, a_dst, N);
    k_deg<<<(E + 255) / 256, 256, 0, stream>>>(ei, E, deg);
    int NB = (N + 255) / 256;
    k_scan1<<<NB, 256, 0, stream>>>(deg, offs, blockSums, N);
    k_scan2<<<1, 512, 0, stream>>>(blockSums, blockScan, NB);
    k_scan3<<<NB, 256, 0, stream>>>(offs, blockScan, N);
    k_scatter<<<(E + 255) / 256, 256, 0, stream>>>(ei, E, a_src, a_dst, offs, cur, csr);
    k_gather<<<(N * 64 + 511) / 512, 512, 0, stream>>>(hb, csr, offs, deg, a_src, a_dst,
                                                       bias, (float*)d_out, N);
}

// Round 5
// 263.156 us; speedup vs baseline: 1.6954x; 1.1421x over previous
//
#include <hip/hip_runtime.h>
#include <hip/hip_bf16.h>

#define NEG_SLOPE 0.2f

typedef __attribute__((ext_vector_type(8))) short bf16x8;
typedef __attribute__((ext_vector_type(4))) float f32x4;

__device__ __forceinline__ float lrelu(float v) { return v > 0.0f ? v : NEG_SLOPE * v; }

__device__ __forceinline__ unsigned bf16pair(float a, float b) {
    unsigned ua = __float_as_uint(a), ub = __float_as_uint(b);
    ua = (ua + 0x7FFFu + ((ua >> 16) & 1u)) >> 16;
    ub = (ub + 0x7FFFu + ((ub >> 16) & 1u)) >> 16;
    return ua | (ub << 16);
}

// ---------------- MFMA GEMM: h=x@W (bf16), fused W-transpose, att logits, deg --
// 256 threads (4 waves), 128 rows x 128 cols per block, K=128 in LDS.
__global__ __launch_bounds__(256) void k_gemm(const float* __restrict__ x,
                                              const float* __restrict__ W,
                                              const float* __restrict__ att_src,
                                              const float* __restrict__ att_dst,
                                              unsigned* __restrict__ hb,
                                              float* __restrict__ a_src,
                                              float* __restrict__ a_dst,
                                              const int* __restrict__ ei,
                                              unsigned* __restrict__ deg,
                                              int N, int E, int EPB) {
    __shared__ unsigned char sm[65536];
    unsigned char* smA = sm;           // A tile: [128 r][128 k] bf16, 16B-chunk XOR swizzle
    unsigned char* smB = sm + 32768;   // B tile: [128 col][128 k] bf16, same swizzle
    int t = threadIdx.x;
    int row0 = blockIdx.x * 128;

    {
        int r = t >> 1, halfc = t & 1;
        int gr = row0 + r;
        // stage A (x -> bf16, swizzled)
#pragma unroll
        for (int j = 0; j < 8; ++j) {
            float4 f0 = {0.f, 0.f, 0.f, 0.f}, f1 = {0.f, 0.f, 0.f, 0.f};
            if (gr < N) {
                f0 = ((const float4*)x)[(size_t)gr * 32 + halfc * 16 + j * 2];
                f1 = ((const float4*)x)[(size_t)gr * 32 + halfc * 16 + j * 2 + 1];
            }
            uint4 u;
            u.x = bf16pair(f0.x, f0.y);
            u.y = bf16pair(f0.z, f0.w);
            u.z = bf16pair(f1.x, f1.y);
            u.w = bf16pair(f1.z, f1.w);
            int c = halfc * 8 + j;
            *(uint4*)&smA[r * 256 + ((c ^ (r & 7)) * 16)] = u;
        }
        // stage B: transpose+convert W fp32 [k][n] -> smB[col][k] bf16 swizzled
        int col = r;
#pragma unroll
        for (int j = 0; j < 8; ++j) {
            int c = halfc * 8 + j;       // chunk: k = c*8 .. c*8+7
            float f[8];
#pragma unroll
            for (int kk = 0; kk < 8; ++kk)
                f[kk] = W[(size_t)(c * 8 + kk) * 128 + col];
            uint4 u;
            u.x = bf16pair(f[0], f[1]);
            u.y = bf16pair(f[2], f[3]);
            u.z = bf16pair(f[4], f[5]);
            u.w = bf16pair(f[6], f[7]);
            *(uint4*)&smB[col * 256 + ((c ^ (col & 7)) * 16)] = u;
        }
    }
    __syncthreads();

    int w = t >> 6, lane = t & 63;
    int lr = lane & 15, lg = lane >> 4;

    f32x4 acc[2][8];
#pragma unroll
    for (int i = 0; i < 2; ++i)
#pragma unroll
        for (int j = 0; j < 8; ++j)
#pragma unroll
            for (int q = 0; q < 4; ++q) acc[i][j][q] = 0.f;

#pragma unroll
    for (int kc = 0; kc < 4; ++kc) {
        bf16x8 av[2], bv[8];
#pragma unroll
        for (int rf = 0; rf < 2; ++rf) {
            int ar = w * 32 + rf * 16 + lr;
            av[rf] = *(const bf16x8*)&smA[ar * 256 + (((kc * 4 + lg) ^ (ar & 7)) * 16)];
        }
#pragma unroll
        for (int cf = 0; cf < 8; ++cf) {
            int bc = cf * 16 + lr;
            bv[cf] = *(const bf16x8*)&smB[bc * 256 + (((kc * 4 + lg) ^ (bc & 7)) * 16)];
        }
#pragma unroll
        for (int rf = 0; rf < 2; ++rf)
#pragma unroll
            for (int cf = 0; cf < 8; ++cf)
                acc[rf][cf] = __builtin_amdgcn_mfma_f32_16x16x32_bf16(av[rf], bv[cf], acc[rf][cf], 0, 0, 0);
    }

    // epilogue: hb (bf16 pairs) + fused a_src/a_dst
    float att_s[8], att_d[8];
#pragma unroll
    for (int cf = 0; cf < 8; ++cf) {
        att_s[cf] = att_src[cf * 16 + lr];
        att_d[cf] = att_dst[cf * 16 + lr];
    }
#pragma unroll
    for (int rf = 0; rf < 2; ++rf) {
#pragma unroll
        for (int reg = 0; reg < 4; ++reg) {
            int row = row0 + w * 32 + rf * 16 + lg * 4 + reg;
            float ps[4], pd[4];
#pragma unroll
            for (int hh = 0; hh < 4; ++hh) {
                ps[hh] = acc[rf][2 * hh][reg] * att_s[2 * hh] + acc[rf][2 * hh + 1][reg] * att_s[2 * hh + 1];
                pd[hh] = acc[rf][2 * hh][reg] * att_d[2 * hh] + acc[rf][2 * hh + 1][reg] * att_d[2 * hh + 1];
            }
#pragma unroll
            for (int m = 1; m <= 8; m <<= 1) {
#pragma unroll
                for (int hh = 0; hh < 4; ++hh) {
                    ps[hh] += __shfl_xor(ps[hh], m);
                    pd[hh] += __shfl_xor(pd[hh], m);
                }
            }
            if (lr == 0 && row < N) {
                ((float4*)a_src)[row] = float4{ps[0], ps[1], ps[2], ps[3]};
                ((float4*)a_dst)[row] = float4{pd[0], pd[1], pd[2], pd[3]};
            }
#pragma unroll
            for (int cf = 0; cf < 8; ++cf) {
                float v = acc[rf][cf][reg];
                float vo = __shfl_xor(v, 1);
                if (!(lane & 1) && row < N)
                    hb[(size_t)row * 64 + cf * 8 + (lr >> 1)] = bf16pair(v, vo);
            }
        }
    }

    // fused degree histogram: this block's slice of edges
    size_t base = (size_t)blockIdx.x * EPB;
    size_t lim = base + EPB;
    if (lim > (size_t)E) lim = E;
    for (size_t i = base + t; i < lim; i += 256)
        atomicAdd(&deg[ei[(size_t)E + i]], 1u);
}

// ---------------- exclusive scan (2 kernels; apply fused downstream) ---------
__global__ void k_scan1(const unsigned* __restrict__ deg, unsigned* __restrict__ part,
                        unsigned* __restrict__ blockSums, int N) {
    __shared__ unsigned s[256];
    int t = threadIdx.x;
    int i = blockIdx.x * 256 + t;
    unsigned v = (i < N) ? deg[i] : 0u;
    s[t] = v;
    __syncthreads();
    for (int off = 1; off < 256; off <<= 1) {
        unsigned a = (t >= off) ? s[t - off] : 0u;
        __syncthreads();
        s[t] += a;
        __syncthreads();
    }
    if (i < N) part[i] = s[t] - v;
    if (t == 255) blockSums[blockIdx.x] = s[255];
}

__global__ void k_scan2(const unsigned* __restrict__ blockSums,
                        unsigned* __restrict__ blockScan, int NB) {
    __shared__ unsigned s[512];
    int t = threadIdx.x;
    unsigned v = (t < NB) ? blockSums[t] : 0u;
    s[t] = v;
    __syncthreads();
    for (int off = 1; off < 512; off <<= 1) {
        unsigned a = (t >= off) ? s[t - off] : 0u;
        __syncthreads();
        s[t] += a;
        __syncthreads();
    }
    if (t < NB) blockScan[t] = s[t] - v;
}

// ---------------- scatter: build 16B CSR entries {src, p01_f16, p23_f16, 0} --
__global__ void k_scatter(const int* __restrict__ ei, int E,
                          const float* __restrict__ a_src, const float* __restrict__ a_dst,
                          const unsigned* __restrict__ part,
                          const unsigned* __restrict__ blockScan,
                          unsigned* __restrict__ cursor, uint4* __restrict__ csr) {
    int e = blockIdx.x * 256 + threadIdx.x;
    if (e >= E) return;
    int s = ei[e];
    int d = ei[(size_t)E + e];
    float4 as = ((const float4*)a_src)[s];
    float4 ad = ((const float4*)a_dst)[d];
    float p0 = __expf(lrelu(as.x + ad.x));
    float p1 = __expf(lrelu(as.y + ad.y));
    float p2 = __expf(lrelu(as.z + ad.z));
    float p3 = __expf(lrelu(as.w + ad.w));
    unsigned p01 = __builtin_bit_cast(unsigned, __builtin_amdgcn_cvt_pkrtz(p0, p1));
    unsigned p23 = __builtin_bit_cast(unsigned, __builtin_amdgcn_cvt_pkrtz(p2, p3));
    unsigned pos = part[d] + blockScan[d >> 8] + atomicAdd(&cursor[d], 1u);
    csr[pos] = uint4{(unsigned)s, p01, p23, 0u};
}

// ---------------- gather: one wave per dst node, clamped 8-wide MLP ----------
__global__ __launch_bounds__(256) void k_gather(const unsigned* __restrict__ hb,
                                                const uint4* __restrict__ csr,
                                                const unsigned* __restrict__ part,
                                                const unsigned* __restrict__ blockScan,
                                                const unsigned* __restrict__ deg,
                                                const float* __restrict__ a_src,
                                                const float* __restrict__ a_dst,
                                                const float* __restrict__ bias,
                                                float* __restrict__ out, int N) {
    int n = (int)((blockIdx.x * 256 + threadIdx.x) >> 6);
    int lane = threadIdx.x & 63;
    if (n >= N) return;
    int head = lane >> 4;
    unsigned off = part[n] + blockScan[n >> 8];
    unsigned end = off + deg[n];
    float ax = 0.f, ay = 0.f, dsum = 0.f;
    for (unsigned b = off; b < end; b += 8) {
        uint4 Ee[8];
#pragma unroll
        for (int i = 0; i < 8; ++i) {
            unsigned idx = b + i;
            if (idx >= end) idx = end - 1;
            Ee[i] = csr[idx];
        }
#pragma unroll
        for (int i = 0; i < 8; ++i) {
            unsigned pw = (head & 2) ? Ee[i].z : Ee[i].y;
            unsigned hv = (head & 1) ? (pw >> 16) : (pw & 0xFFFFu);
            float p = (float)__builtin_bit_cast(_Float16, (unsigned short)hv);
            p = (b + i < end) ? p : 0.f;
            unsigned u = hb[(size_t)Ee[i].x * 64 + lane];
            ax = fmaf(p, __uint_as_float(u << 16), ax);
            ay = fmaf(p, __uint_as_float(u & 0xFFFF0000u), ay);
            dsum += p;
        }
    }
    // self loop (fp32 p)
    float p_self = __expf(lrelu(a_src[n * 4 + head] + a_dst[n * 4 + head]));
    unsigned us = hb[(size_t)n * 64 + lane];
    ax = fmaf(p_self, __uint_as_float(us << 16), ax);
    ay = fmaf(p_self, __uint_as_float(us & 0xFFFF0000u), ay);
    dsum += p_self;
    float inv = 1.0f / dsum;
    float2 b2 = ((const float2*)bias)[lane];
    float ox = ax * inv + b2.x;
    float oy = ay * inv + b2.y;
    ox = ox > 0.f ? ox : (__expf(ox) - 1.0f);
    oy = oy > 0.f ? oy : (__expf(oy) - 1.0f);
    ((float2*)out)[(size_t)n * 64 + lane] = float2{ox, oy};
}

extern "C" void kernel_launch(void* const* d_in, const int* in_sizes, int n_in,
                              void* d_out, int out_size, void* d_ws, size_t ws_size,
                              hipStream_t stream) {
    const float* x = (const float*)d_in[0];
    const int* ei = (const int*)d_in[1];
    const float* W = (const float*)d_in[2];
    const float* att_src = (const float*)d_in[3];
    const float* att_dst = (const float*)d_in[4];
    const float* bias = (const float*)d_in[5];
    int N = in_sizes[0] / 128;
    int E = in_sizes[1] / 2;

    char* ws = (char*)d_ws;
    size_t o = 0;
    unsigned* hb = (unsigned*)(ws + o);   o += (size_t)N * 64 * 4;   // 25.6 MB bf16 h
    float* a_src = (float*)(ws + o);      o += (size_t)N * 4 * 4;
    float* a_dst = (float*)(ws + o);      o += (size_t)N * 4 * 4;
    uint4* csr = (uint4*)(ws + o);        o += (size_t)E * 16;       // 25.6 MB
    unsigned* deg = (unsigned*)(ws + o);  o += (size_t)N * 4;
    unsigned* cur = (unsigned*)(ws + o);  o += (size_t)N * 4;        // adjacent to deg
    unsigned* part = (unsigned*)(ws + o); o += (size_t)N * 4;
    unsigned* blockSums = (unsigned*)(ws + o); o += 2048;
    unsigned* blockScan = (unsigned*)(ws + o); o += 2048;

    hipMemsetAsync(deg, 0, (size_t)N * 8, stream);  // deg + cur

    int nbG = (N + 127) / 128;                 // 782
    int EPB = (E + nbG - 1) / nbG;             // 2047
    k_gemm<<<nbG, 256, 0, stream>>>(x, W, att_src, att_dst, hb, a_src, a_dst, ei, deg, N, E, EPB);
    int NB = (N + 255) / 256;                  // 391
    k_scan1<<<NB, 256, 0, stream>>>(deg, part, blockSums, N);
    k_scan2<<<1, 512, 0, stream>>>(blockSums, blockScan, NB);
    k_scatter<<<(E + 255) / 256, 256, 0, stream>>>(ei, E, a_src, a_dst, part, blockScan, cur, csr);
    k_gather<<<(N * 64 + 255) / 256, 256, 0, stream>>>(hb, csr, part, blockScan, deg, a_src,
                                                       a_dst, bias, (float*)d_out, N);
}